// Round 2
// baseline (379.202 us; speedup 1.0000x reference)
//
#include <hip/hip_runtime.h>
#include <hip/hip_bf16.h>
#include <math.h>

// ---------------- problem constants ----------------
#define BATCH   8
#define SEQL    8192
#define DOUTD   512
#define DHID    256
#define MTOT    (BATCH*SEQL)      // 65536
#define CHUNKS  128               // scan chunks per sequence
#define CHUNKLN 64                // SEQL/CHUNKS
#define SQUAR   6                 // log2(CHUNKLN)

typedef __bf16 bh;
typedef __bf16 bh8 __attribute__((ext_vector_type(8)));
typedef float  f32x4 __attribute__((ext_vector_type(4)));

// ---------------- x fp32 -> bf16 ----------------
__global__ void conv_x_kernel(const float4* __restrict__ x, bh* __restrict__ xh) {
    long i = (long)blockIdx.x * 256 + threadIdx.x;   // each thread: 8 floats
    float4 a = x[2 * i], c = x[2 * i + 1];
    bh8 o;
    o[0] = (bh)a.x; o[1] = (bh)a.y; o[2] = (bh)a.z; o[3] = (bh)a.w;
    o[4] = (bh)c.x; o[5] = (bh)c.y; o[6] = (bh)c.z; o[7] = (bh)c.w;
    *(bh8*)(xh + i * 8) = o;
}

// ---------------- small precompute: lam, lam^S, bB, bD ----------------
__global__ void prep0_kernel(const float* __restrict__ nu_log, const float* __restrict__ theta_log,
                             const float* __restrict__ gamma_log, const float* __restrict__ Bre,
                             const float* __restrict__ Bim, const float* __restrict__ bvec,
                             const float* __restrict__ Dvec,
                             float* lamRe, float* lamIm, float* lamSRe, float* lamSIm,
                             float* gamma, float* bB, float* bD) {
    int t = threadIdx.x;
    if (t < 512) bD[t] = bvec[t] * Dvec[t];
    if (t < 256) {
        float nu = expf(nu_log[t]);
        float th = expf(theta_log[t]);
        float mag = expf(-nu);
        float lr = mag * cosf(th), li = mag * sinf(th);
        lamRe[t] = lr; lamIm[t] = li;
        float pr = lr, pi = li;
        for (int s = 0; s < SQUAR; ++s) { float nr = pr*pr - pi*pi, ni = 2.f*pr*pi; pr = nr; pi = ni; }
        lamSRe[t] = pr; lamSIm[t] = pi;
        float g = expf(gamma_log[t]);
        gamma[t] = g;
        float sre = 0.f, sim = 0.f;
        for (int k = 0; k < 512; ++k) {
            float bk = bvec[k];
            sre += bk * Bre[t * 512 + k];
            sim += bk * Bim[t * 512 + k];
        }
        bB[t] = sre * g; bB[t + 256] = sim * g;
    }
}

// WBt[c][j] (bf16, [512][512]) = sum_k W[j,k]*B_{re/im}[c mod 256, k] * gamma
__global__ void prepWB_kernel(const float* __restrict__ W, const float* __restrict__ Bre,
                              const float* __restrict__ Bim, const float* __restrict__ gamma,
                              bh* __restrict__ WBt) {
    int e = blockIdx.x * 256 + threadIdx.x;   // over 512*512
    int c = e >> 9, j = e & 511;
    const float* Bp = (c < 256) ? (Bre + c * 512) : (Bim + (c - 256) * 512);
    float g = gamma[c & 255];
    float s = 0.f;
    for (int k = 0; k < 512; ++k) s += W[j * 512 + k] * Bp[k];
    WBt[e] = (bh)(s * g);
}

// WcT[c][k'] (bf16, [512][1024]): k'<256: Cre[c][k']; <512: -Cim[c][k'-256]; else W[k'-512][c]*D[c]
__global__ void prepWC_kernel(const float* __restrict__ Cre, const float* __restrict__ Cim,
                              const float* __restrict__ W, const float* __restrict__ Dvec,
                              bh* __restrict__ WcT) {
    int e = blockIdx.x * 256 + threadIdx.x;   // over 512*1024
    int c = e >> 10, kp = e & 1023;
    float v;
    if (kp < 256)       v = Cre[c * 256 + kp];
    else if (kp < 512)  v = -Cim[c * 256 + (kp - 256)];
    else                v = W[(kp - 512) * 512 + c] * Dvec[c];
    WcT[e] = (bh)v;
}

// ---------------- bf16 MFMA GEMM, 128x128 tile, BK=32, 4 waves ----------------
// LDS slot-XOR swizzle, identical on write & read (self-cancelling); k-permutation
// of the MFMA input regs is irrelevant as long as A and B use the same mapping.
__device__ __forceinline__ int swz_off(int row, int slot) {
    return (row * 4 + (slot ^ ((row >> 1) & 3))) * 8;   // bf16-element offset
}

template<int KTOT, bool SPLIT_A, bool OUT_F32>
__global__ void gemm_kernel(const bh* __restrict__ A0, const bh* __restrict__ A1,
                            const bh* __restrict__ Bw, const float* __restrict__ bias,
                            float* __restrict__ outF, bh* __restrict__ outH) {
    __shared__ alignas(16) bh lds[8192];     // A tile [128][32] + B tile [128][32]
    const int tid = threadIdx.x;
    const int l = tid & 63, w = tid >> 6;
    const int wm = w >> 1, wn = w & 1;
    const int rowBase = blockIdx.y * 128, colBase = blockIdx.x * 128;
    const int srow = tid >> 2, sslot = tid & 3;
    const int rsub = l & 15, g = l >> 4;
    f32x4 acc[4][4] = {};

    for (int kt = 0; kt < KTOT / 32; ++kt) {
        const int k0 = kt * 32;
        const bh* As = A0; int kk = k0;
        if (SPLIT_A && k0 >= 512) { As = A1; kk = k0 - 512; }
#pragma unroll
        for (int h = 0; h < 2; ++h) {
            const int r = srow + h * 64;
            bh8 va = *(const bh8*)(As + (size_t)(rowBase + r) * 512 + kk + sslot * 8);
            *(bh8*)&lds[swz_off(r, sslot)] = va;
            bh8 vb = *(const bh8*)(Bw + (size_t)(colBase + r) * KTOT + k0 + sslot * 8);
            *(bh8*)&lds[4096 + swz_off(r, sslot)] = vb;
        }
        __syncthreads();
        bh8 af[4], bfr[4];
#pragma unroll
        for (int m = 0; m < 4; ++m) af[m]  = *(const bh8*)&lds[swz_off(wm * 64 + m * 16 + rsub, g)];
#pragma unroll
        for (int n = 0; n < 4; ++n) bfr[n] = *(const bh8*)&lds[4096 + swz_off(wn * 64 + n * 16 + rsub, g)];
#pragma unroll
        for (int m = 0; m < 4; ++m)
#pragma unroll
            for (int n = 0; n < 4; ++n)
                acc[m][n] = __builtin_amdgcn_mfma_f32_16x16x32_bf16(af[m], bfr[n], acc[m][n], 0, 0, 0);
        __syncthreads();
    }

#pragma unroll
    for (int m = 0; m < 4; ++m)
#pragma unroll
        for (int j = 0; j < 4; ++j) {
            const int row = rowBase + wm * 64 + m * 16 + g * 4 + j;
#pragma unroll
            for (int n = 0; n < 4; ++n) {
                const int col = colBase + wn * 64 + n * 16 + rsub;
                float v = acc[m][n][j] + bias[col];
                if (OUT_F32) outF[(size_t)row * 512 + col] = v;
                else         outH[(size_t)row * 512 + col] = (bh)v;
            }
        }
}

// ---------------- chunked complex scan (3 passes) ----------------
// pass 1: per-chunk local carry (fp32) from bf16 Bu
__global__ void scan1_kernel(const bh* __restrict__ Bu, const float* __restrict__ lamRe,
                             const float* __restrict__ lamIm, float* __restrict__ carRe,
                             float* __restrict__ carIm) {
    int b = blockIdx.x >> 7, c = blockIdx.x & (CHUNKS - 1);
    int n = threadIdx.x;
    float lr = lamRe[n], li = lamIm[n];
    float hr = 0.f, hi = 0.f;
    const bh* p = Bu + ((size_t)(b * SEQL + c * CHUNKLN)) * 512;
    for (int i = 0; i < CHUNKLN; ++i) {
        float br = (float)p[n], bi = (float)p[n + 256];
        float nr = lr * hr - li * hi + br;
        float ni = lr * hi + li * hr + bi;
        hr = nr; hi = ni; p += 512;
    }
    carRe[(size_t)blockIdx.x * 256 + n] = hr;
    carIm[(size_t)blockIdx.x * 256 + n] = hi;
}

// pass 2: scan over chunk carries with lam^CHUNKLN -> per-chunk initial state
__global__ void scan2_kernel(const float* __restrict__ carRe, const float* __restrict__ carIm,
                             const float* __restrict__ lamSRe, const float* __restrict__ lamSIm,
                             float* __restrict__ iniRe, float* __restrict__ iniIm) {
    int b = blockIdx.x, n = threadIdx.x;
    float lr = lamSRe[n], li = lamSIm[n];
    float hr = 0.f, hi = 0.f;
    for (int c = 0; c < CHUNKS; ++c) {
        size_t idx = ((size_t)b * CHUNKS + c) * 256 + n;
        iniRe[idx] = hr; iniIm[idx] = hi;
        float cr = carRe[idx], ci = carIm[idx];
        float nr = lr * hr - li * hi + cr;
        float ni = lr * hi + li * hr + ci;
        hr = nr; hi = ni;
    }
}

// pass 3: recompute local scan with carry-in, write h (bf16, in-place over Bu) + final-state tail
// Tail layout: PLANAR — re[0:2048] then im[2048:4096] (stack([h.real, h.imag]) flattening).
// If the harness counts complex elements singly (tailN==2048), write real parts only.
__global__ void scan3_kernel(bh* __restrict__ Bu, const float* __restrict__ lamRe,
                             const float* __restrict__ lamIm, const float* __restrict__ iniRe,
                             const float* __restrict__ iniIm, float* __restrict__ outTail,
                             int tailN) {
    int b = blockIdx.x >> 7, c = blockIdx.x & (CHUNKS - 1);
    int n = threadIdx.x;
    float lr = lamRe[n], li = lamIm[n];
    size_t idx = (size_t)blockIdx.x * 256 + n;
    float hr = iniRe[idx], hi = iniIm[idx];
    bh* p = Bu + ((size_t)(b * SEQL + c * CHUNKLN)) * 512;
    for (int i = 0; i < CHUNKLN; ++i) {
        float br = (float)p[n], bi = (float)p[n + 256];
        float nr = lr * hr - li * hi + br;
        float ni = lr * hi + li * hr + bi;
        hr = nr; hi = ni;
        p[n] = (bh)hr; p[n + 256] = (bh)hi;
        p += 512;
    }
    if (c == CHUNKS - 1) {                 // h[:, L-1]
        if (tailN >= 4096) {               // planar: all re, then all im
            outTail[b * 256 + n]        = hr;
            outTail[2048 + b * 256 + n] = hi;
        } else {                           // complex counted as one elem: real only
            outTail[b * 256 + n] = hr;
        }
    }
}

// ---------------- launch ----------------
extern "C" void kernel_launch(void* const* d_in, const int* in_sizes, int n_in,
                              void* d_out, int out_size, void* d_ws, size_t ws_size,
                              hipStream_t stream) {
    const float* x        = (const float*)d_in[0];
    const float* W        = (const float*)d_in[1];
    const float* bvec     = (const float*)d_in[2];
    const float* nu_log   = (const float*)d_in[3];
    const float* theta_lg = (const float*)d_in[4];
    const float* gamma_lg = (const float*)d_in[5];
    const float* Bre      = (const float*)d_in[6];
    const float* Bim      = (const float*)d_in[7];
    const float* Cre      = (const float*)d_in[8];
    const float* Cim      = (const float*)d_in[9];
    const float* Dvec     = (const float*)d_in[10];

    char* ws = (char*)d_ws;
    bh* xh   = (bh*)(ws);                                   // 64 MB
    bh* bu   = (bh*)(ws + 67108864);                        // 64 MB (becomes h in-place)
    bh* wbt  = (bh*)(ws + 134217728);                       // 512 KB
    bh* wct  = (bh*)(ws + 134217728 + 524288);              // 1 MB
    float* sm = (float*)(ws + 134217728 + 524288 + 1048576);
    float* bB = sm;               // 512
    float* bD = sm + 512;         // 512
    float* lamRe  = sm + 1024;    // 256
    float* lamIm  = sm + 1280;
    float* lamSRe = sm + 1536;
    float* lamSIm = sm + 1792;
    float* gamma  = sm + 2048;    // 256
    float* carRe  = sm + 2304;                 // 8*128*256 each
    float* carIm  = carRe + (size_t)BATCH * CHUNKS * 256;
    float* iniRe  = carIm + (size_t)BATCH * CHUNKS * 256;
    float* iniIm  = iniRe + (size_t)BATCH * CHUNKS * 256;

    float* outF    = (float*)d_out;
    float* outTail = outF + (size_t)MTOT * DOUTD;
    int tailN = out_size - MTOT * DOUTD;       // 4096 (float view) or 2048 (complex-counted)

    conv_x_kernel<<<16384, 256, 0, stream>>>((const float4*)x, xh);
    prep0_kernel<<<1, 512, 0, stream>>>(nu_log, theta_lg, gamma_lg, Bre, Bim, bvec, Dvec,
                                        lamRe, lamIm, lamSRe, lamSIm, gamma, bB, bD);
    prepWB_kernel<<<1024, 256, 0, stream>>>(W, Bre, Bim, gamma, wbt);
    prepWC_kernel<<<2048, 256, 0, stream>>>(Cre, Cim, W, Dvec, wct);

    gemm_kernel<512, false, false><<<dim3(4, 512), 256, 0, stream>>>(xh, nullptr, wbt, bB, nullptr, bu);

    scan1_kernel<<<BATCH * CHUNKS, 256, 0, stream>>>(bu, lamRe, lamIm, carRe, carIm);
    scan2_kernel<<<BATCH, 256, 0, stream>>>(carRe, carIm, lamSRe, lamSIm, iniRe, iniIm);
    scan3_kernel<<<BATCH * CHUNKS, 256, 0, stream>>>(bu, lamRe, lamIm, iniRe, iniIm, outTail, tailN);

    gemm_kernel<1024, true, true><<<dim3(4, 512), 256, 0, stream>>>(bu, xh, wct, bD, outF, nullptr);
}

// Round 4
// 364.743 us; speedup vs baseline: 1.0396x; 1.0396x over previous
//
#include <hip/hip_runtime.h>
#include <hip/hip_bf16.h>
#include <math.h>

// ---------------- problem constants ----------------
#define BATCH   8
#define SEQL    8192
#define DOUTD   512
#define DHID    256
#define MTOT    (BATCH*SEQL)      // 65536
#define CHUNKS  128               // scan chunks per sequence
#define CHUNKLN 64                // SEQL/CHUNKS
#define SQUAR   6                 // log2(CHUNKLN)

typedef __bf16 bh;
typedef __bf16 bh8 __attribute__((ext_vector_type(8)));
typedef float  f32x4 __attribute__((ext_vector_type(4)));

// ---------------- x fp32 -> bf16 ----------------
__global__ void conv_x_kernel(const float4* __restrict__ x, bh* __restrict__ xh) {
    long i = (long)blockIdx.x * 256 + threadIdx.x;   // each thread: 8 floats
    float4 a = x[2 * i], c = x[2 * i + 1];
    bh8 o;
    o[0] = (bh)a.x; o[1] = (bh)a.y; o[2] = (bh)a.z; o[3] = (bh)a.w;
    o[4] = (bh)c.x; o[5] = (bh)c.y; o[6] = (bh)c.z; o[7] = (bh)c.w;
    *(bh8*)(xh + i * 8) = o;
}

// ---------------- small precompute: lam, lam^S, bB, bD ----------------
__global__ void prep0_kernel(const float* __restrict__ nu_log, const float* __restrict__ theta_log,
                             const float* __restrict__ gamma_log, const float* __restrict__ Bre,
                             const float* __restrict__ Bim, const float* __restrict__ bvec,
                             const float* __restrict__ Dvec,
                             float* lamRe, float* lamIm, float* lamSRe, float* lamSIm,
                             float* gamma, float* bB, float* bD) {
    int t = threadIdx.x;
    if (t < 512) bD[t] = bvec[t] * Dvec[t];
    if (t < 256) {
        float nu = expf(nu_log[t]);
        float th = expf(theta_log[t]);
        float mag = expf(-nu);
        float lr = mag * cosf(th), li = mag * sinf(th);
        lamRe[t] = lr; lamIm[t] = li;
        float pr = lr, pi = li;
        for (int s = 0; s < SQUAR; ++s) { float nr = pr*pr - pi*pi, ni = 2.f*pr*pi; pr = nr; pi = ni; }
        lamSRe[t] = pr; lamSIm[t] = pi;
        float g = expf(gamma_log[t]);
        gamma[t] = g;
        float sre = 0.f, sim = 0.f;
        for (int k = 0; k < 512; ++k) {
            float bk = bvec[k];
            sre += bk * Bre[t * 512 + k];
            sim += bk * Bim[t * 512 + k];
        }
        bB[t] = sre * g; bB[t + 256] = sim * g;
    }
}

// WBt[c][j] (bf16, [512][512]) = sum_k W[j,k]*B_{re/im}[c mod 256, k] * gamma
__global__ void prepWB_kernel(const float* __restrict__ W, const float* __restrict__ Bre,
                              const float* __restrict__ Bim, const float* __restrict__ gamma,
                              bh* __restrict__ WBt) {
    int e = blockIdx.x * 256 + threadIdx.x;   // over 512*512
    int c = e >> 9, j = e & 511;
    const float* Bp = (c < 256) ? (Bre + c * 512) : (Bim + (c - 256) * 512);
    float g = gamma[c & 255];
    float s = 0.f;
    for (int k = 0; k < 512; ++k) s += W[j * 512 + k] * Bp[k];
    WBt[e] = (bh)(s * g);
}

// WcT[c][k'] (bf16, [512][1024]): k'<256: Cre[c][k']; <512: -Cim[c][k'-256]; else W[k'-512][c]*D[c]
__global__ void prepWC_kernel(const float* __restrict__ Cre, const float* __restrict__ Cim,
                              const float* __restrict__ W, const float* __restrict__ Dvec,
                              bh* __restrict__ WcT) {
    int e = blockIdx.x * 256 + threadIdx.x;   // over 512*1024
    int c = e >> 10, kp = e & 1023;
    float v;
    if (kp < 256)       v = Cre[c * 256 + kp];
    else if (kp < 512)  v = -Cim[c * 256 + (kp - 256)];
    else                v = W[(kp - 512) * 512 + c] * Dvec[c];
    WcT[e] = (bh)v;
}

// ---------------- bf16 MFMA GEMM, m97 structure ----------------
// 128x128 tile, BK=64, 4 waves, global_load_lds(16B) staging into LINEAR LDS
// (T2 swizzle is null at 2-phase per regime gate), banded XCD swizzle so the 4
// col-tiles sharing an A row-band land on the same XCD's L2.
// MFMA input k-permutation irrelevant: A and B frags use the identical
// (rsub,g)->k mapping (verified correct in round 2).

template<int KTOT, bool SPLIT_A, bool OUT_F32>
__global__ __launch_bounds__(256) void gemm_kernel(const bh* __restrict__ A0, const bh* __restrict__ A1,
                            const bh* __restrict__ Bw, const float* __restrict__ bias,
                            float* __restrict__ outF, bh* __restrict__ outH) {
    __shared__ alignas(16) bh lds[16384];     // A tile [128][64] @0 + B tile [128][64] @8192
    const int tid = threadIdx.x;
    const int l = tid & 63, w = tid >> 6;
    const int wm = w >> 1, wn = w & 1;
    // banded XCD swizzle: consecutive swz ids (sharing an A band) on one XCD
    const int bid = blockIdx.x, nwg = gridDim.x;
    const int swz = (bid & 7) * (nwg >> 3) + (bid >> 3);
    const int rowBase = (swz >> 2) * 128;     // 512 row bands
    const int colBase = (swz & 3) * 128;      // 4 col tiles
    const int lr8 = l >> 3;                   // row within 8-row segment
    const int lc8 = (l & 7) * 8;              // bf16 col within row
    const int rsub = l & 15, g = l >> 4;
    f32x4 acc[4][4] = {};

    for (int kt = 0; kt < KTOT / 64; ++kt) {
        const int k0 = kt * 64;
        const bh* As = A0; int kk = k0;
        if (SPLIT_A && k0 >= 512) { As = A1; kk = k0 - 512; }
        __syncthreads();   // prev iter's reads done before overwrite
#pragma unroll
        for (int i = 0; i < 4; ++i) {
            const int r = w * 32 + i * 8;     // segment base row (wave-uniform)
            const bh* ga = As + (size_t)(rowBase + r + lr8) * 512 + kk + lc8;
            const bh* gb = Bw + (size_t)(colBase + r + lr8) * KTOT + k0 + lc8;
            __builtin_amdgcn_global_load_lds(
                (const __attribute__((address_space(1))) void*)ga,
                (__attribute__((address_space(3))) void*)&lds[r * 64], 16, 0, 0);
            __builtin_amdgcn_global_load_lds(
                (const __attribute__((address_space(1))) void*)gb,
                (__attribute__((address_space(3))) void*)&lds[8192 + r * 64], 16, 0, 0);
        }
        __syncthreads();   // vmcnt(0) drained here -> tiles visible
#pragma unroll
        for (int ks = 0; ks < 2; ++ks) {
            bh8 af[4], bfr[4];
#pragma unroll
            for (int m = 0; m < 4; ++m)
                af[m] = *(const bh8*)&lds[(wm * 64 + m * 16 + rsub) * 64 + ks * 32 + g * 8];
#pragma unroll
            for (int n = 0; n < 4; ++n)
                bfr[n] = *(const bh8*)&lds[8192 + (wn * 64 + n * 16 + rsub) * 64 + ks * 32 + g * 8];
#pragma unroll
            for (int m = 0; m < 4; ++m)
#pragma unroll
                for (int n = 0; n < 4; ++n)
                    acc[m][n] = __builtin_amdgcn_mfma_f32_16x16x32_bf16(af[m], bfr[n], acc[m][n], 0, 0, 0);
        }
    }

#pragma unroll
    for (int m = 0; m < 4; ++m)
#pragma unroll
        for (int j = 0; j < 4; ++j) {
            const int row = rowBase + wm * 64 + m * 16 + g * 4 + j;
#pragma unroll
            for (int n = 0; n < 4; ++n) {
                const int col = colBase + wn * 64 + n * 16 + rsub;
                float v = acc[m][n][j] + bias[col];
                if (OUT_F32) outF[(size_t)row * 512 + col] = v;
                else         outH[(size_t)row * 512 + col] = (bh)v;
            }
        }
}

// ---------------- chunked complex scan (3 passes) ----------------
__global__ void scan1_kernel(const bh* __restrict__ Bu, const float* __restrict__ lamRe,
                             const float* __restrict__ lamIm, float* __restrict__ carRe,
                             float* __restrict__ carIm) {
    int b = blockIdx.x >> 7, c = blockIdx.x & (CHUNKS - 1);
    int n = threadIdx.x;
    float lr = lamRe[n], li = lamIm[n];
    float hr = 0.f, hi = 0.f;
    const bh* p = Bu + ((size_t)(b * SEQL + c * CHUNKLN)) * 512;
    for (int i = 0; i < CHUNKLN; ++i) {
        float br = (float)p[n], bi = (float)p[n + 256];
        float nr = lr * hr - li * hi + br;
        float ni = lr * hi + li * hr + bi;
        hr = nr; hi = ni; p += 512;
    }
    carRe[(size_t)blockIdx.x * 256 + n] = hr;
    carIm[(size_t)blockIdx.x * 256 + n] = hi;
}

__global__ void scan2_kernel(const float* __restrict__ carRe, const float* __restrict__ carIm,
                             const float* __restrict__ lamSRe, const float* __restrict__ lamSIm,
                             float* __restrict__ iniRe, float* __restrict__ iniIm) {
    int b = blockIdx.x, n = threadIdx.x;
    float lr = lamSRe[n], li = lamSIm[n];
    float hr = 0.f, hi = 0.f;
    for (int c = 0; c < CHUNKS; ++c) {
        size_t idx = ((size_t)b * CHUNKS + c) * 256 + n;
        iniRe[idx] = hr; iniIm[idx] = hi;
        float cr = carRe[idx], ci = carIm[idx];
        float nr = lr * hr - li * hi + cr;
        float ni = lr * hi + li * hr + ci;
        hr = nr; hi = ni;
    }
}

// pass 3: recompute local scan with carry-in, write h (bf16, in-place over Bu) + tail (planar)
__global__ void scan3_kernel(bh* __restrict__ Bu, const float* __restrict__ lamRe,
                             const float* __restrict__ lamIm, const float* __restrict__ iniRe,
                             const float* __restrict__ iniIm, float* __restrict__ outTail,
                             int tailN) {
    int b = blockIdx.x >> 7, c = blockIdx.x & (CHUNKS - 1);
    int n = threadIdx.x;
    float lr = lamRe[n], li = lamIm[n];
    size_t idx = (size_t)blockIdx.x * 256 + n;
    float hr = iniRe[idx], hi = iniIm[idx];
    bh* p = Bu + ((size_t)(b * SEQL + c * CHUNKLN)) * 512;
    for (int i = 0; i < CHUNKLN; ++i) {
        float br = (float)p[n], bi = (float)p[n + 256];
        float nr = lr * hr - li * hi + br;
        float ni = lr * hi + li * hr + bi;
        hr = nr; hi = ni;
        p[n] = (bh)hr; p[n + 256] = (bh)hi;
        p += 512;
    }
    if (c == CHUNKS - 1) {                 // h[:, L-1]
        if (tailN >= 4096) {               // planar: all re, then all im
            outTail[b * 256 + n]        = hr;
            outTail[2048 + b * 256 + n] = hi;
        } else {
            outTail[b * 256 + n] = hr;
        }
    }
}

// ---------------- launch ----------------
extern "C" void kernel_launch(void* const* d_in, const int* in_sizes, int n_in,
                              void* d_out, int out_size, void* d_ws, size_t ws_size,
                              hipStream_t stream) {
    const float* x        = (const float*)d_in[0];
    const float* W        = (const float*)d_in[1];
    const float* bvec     = (const float*)d_in[2];
    const float* nu_log   = (const float*)d_in[3];
    const float* theta_lg = (const float*)d_in[4];
    const float* gamma_lg = (const float*)d_in[5];
    const float* Bre      = (const float*)d_in[6];
    const float* Bim      = (const float*)d_in[7];
    const float* Cre      = (const float*)d_in[8];
    const float* Cim      = (const float*)d_in[9];
    const float* Dvec     = (const float*)d_in[10];

    char* ws = (char*)d_ws;
    bh* xh   = (bh*)(ws);                                   // 64 MB
    bh* bu   = (bh*)(ws + 67108864);                        // 64 MB (becomes h in-place)
    bh* wbt  = (bh*)(ws + 134217728);                       // 512 KB
    bh* wct  = (bh*)(ws + 134217728 + 524288);              // 1 MB
    float* sm = (float*)(ws + 134217728 + 524288 + 1048576);
    float* bB = sm;               // 512
    float* bD = sm + 512;         // 512
    float* lamRe  = sm + 1024;    // 256
    float* lamIm  = sm + 1280;
    float* lamSRe = sm + 1536;
    float* lamSIm = sm + 1792;
    float* gamma  = sm + 2048;    // 256
    float* carRe  = sm + 2304;                 // 8*128*256 each
    float* carIm  = carRe + (size_t)BATCH * CHUNKS * 256;
    float* iniRe  = carIm + (size_t)BATCH * CHUNKS * 256;
    float* iniIm  = iniRe + (size_t)BATCH * CHUNKS * 256;

    float* outF    = (float*)d_out;
    float* outTail = outF + (size_t)MTOT * DOUTD;
    int tailN = out_size - MTOT * DOUTD;       // 4096 (float view) or 2048

    conv_x_kernel<<<16384, 256, 0, stream>>>((const float4*)x, xh);
    prep0_kernel<<<1, 512, 0, stream>>>(nu_log, theta_lg, gamma_lg, Bre, Bim, bvec, Dvec,
                                        lamRe, lamIm, lamSRe, lamSIm, gamma, bB, bD);
    prepWB_kernel<<<1024, 256, 0, stream>>>(W, Bre, Bim, gamma, wbt);
    prepWC_kernel<<<2048, 256, 0, stream>>>(Cre, Cim, W, Dvec, wct);

    gemm_kernel<512, false, false><<<2048, 256, 0, stream>>>(xh, nullptr, wbt, bB, nullptr, bu);

    scan1_kernel<<<BATCH * CHUNKS, 256, 0, stream>>>(bu, lamRe, lamIm, carRe, carIm);
    scan2_kernel<<<BATCH, 256, 0, stream>>>(carRe, carIm, lamSRe, lamSIm, iniRe, iniIm);
    scan3_kernel<<<BATCH * CHUNKS, 256, 0, stream>>>(bu, lamRe, lamIm, iniRe, iniIm, outTail, tailN);

    gemm_kernel<1024, true, true><<<2048, 256, 0, stream>>>(bu, xh, wct, bD, outF, nullptr);
}

// Round 5
// 343.789 us; speedup vs baseline: 1.1030x; 1.0609x over previous
//
#include <hip/hip_runtime.h>
#include <hip/hip_bf16.h>
#include <math.h>

// ---------------- problem constants ----------------
#define BATCH   8
#define SEQL    8192
#define DOUTD   512
#define DHID    256
#define MTOT    (BATCH*SEQL)      // 65536
#define CHUNKS  128               // scan chunks per sequence
#define CHUNKLN 64                // SEQL/CHUNKS
#define SQUAR   6                 // log2(CHUNKLN)

typedef __bf16 bh;
typedef __bf16 bh8 __attribute__((ext_vector_type(8)));
typedef float  f32x4 __attribute__((ext_vector_type(4)));

// ---------------- x fp32 -> bf16 ----------------
__global__ void conv_x_kernel(const float4* __restrict__ x, bh* __restrict__ xh) {
    long i = (long)blockIdx.x * 256 + threadIdx.x;   // each thread: 8 floats
    float4 a = x[2 * i], c = x[2 * i + 1];
    bh8 o;
    o[0] = (bh)a.x; o[1] = (bh)a.y; o[2] = (bh)a.z; o[3] = (bh)a.w;
    o[4] = (bh)c.x; o[5] = (bh)c.y; o[6] = (bh)c.z; o[7] = (bh)c.w;
    *(bh8*)(xh + i * 8) = o;
}

// ---------------- small precompute: lam, lam^S, bB, bD ----------------
__global__ void prep0_kernel(const float* __restrict__ nu_log, const float* __restrict__ theta_log,
                             const float* __restrict__ gamma_log, const float* __restrict__ Bre,
                             const float* __restrict__ Bim, const float* __restrict__ bvec,
                             const float* __restrict__ Dvec,
                             float* lamRe, float* lamIm, float* lamSRe, float* lamSIm,
                             float* gamma, float* bB, float* bD) {
    int t = threadIdx.x;
    if (t < 512) bD[t] = bvec[t] * Dvec[t];
    if (t < 256) {
        float nu = expf(nu_log[t]);
        float th = expf(theta_log[t]);
        float mag = expf(-nu);
        float lr = mag * cosf(th), li = mag * sinf(th);
        lamRe[t] = lr; lamIm[t] = li;
        float pr = lr, pi = li;
        for (int s = 0; s < SQUAR; ++s) { float nr = pr*pr - pi*pi, ni = 2.f*pr*pi; pr = nr; pi = ni; }
        lamSRe[t] = pr; lamSIm[t] = pi;
        float g = expf(gamma_log[t]);
        gamma[t] = g;
        float sre = 0.f, sim = 0.f;
        for (int k = 0; k < 512; ++k) {
            float bk = bvec[k];
            sre += bk * Bre[t * 512 + k];
            sim += bk * Bim[t * 512 + k];
        }
        bB[t] = sre * g; bB[t + 256] = sim * g;
    }
}

// WBt[c][j] (bf16, [512][512]) = sum_k W[j,k]*B_{re/im}[c mod 256, k] * gamma
__global__ void prepWB_kernel(const float* __restrict__ W, const float* __restrict__ Bre,
                              const float* __restrict__ Bim, const float* __restrict__ gamma,
                              bh* __restrict__ WBt) {
    int e = blockIdx.x * 256 + threadIdx.x;   // over 512*512
    int c = e >> 9, j = e & 511;
    const float* Bp = (c < 256) ? (Bre + c * 512) : (Bim + (c - 256) * 512);
    float g = gamma[c & 255];
    float s = 0.f;
    for (int k = 0; k < 512; ++k) s += W[j * 512 + k] * Bp[k];
    WBt[e] = (bh)(s * g);
}

// WcT[c][k'] (bf16, [512][1024]): k'<256: Cre[c][k']; <512: -Cim[c][k'-256]; else W[k'-512][c]*D[c]
__global__ void prepWC_kernel(const float* __restrict__ Cre, const float* __restrict__ Cim,
                              const float* __restrict__ W, const float* __restrict__ Dvec,
                              bh* __restrict__ WcT) {
    int e = blockIdx.x * 256 + threadIdx.x;   // over 512*1024
    int c = e >> 10, kp = e & 1023;
    float v;
    if (kp < 256)       v = Cre[c * 256 + kp];
    else if (kp < 512)  v = -Cim[c * 256 + (kp - 256)];
    else                v = W[(kp - 512) * 512 + c] * Dvec[c];
    WcT[e] = (bh)v;
}

// ---------------- bf16 MFMA GEMM, 2-phase pipelined (T3 minimum recipe) ----------------
// 128x128 tile, BK=64, 4 waves, DOUBLE-buffered LDS (64KB), global_load_lds(16B).
// Per K-step: STAGE(buf^1, t+1) issued BEFORE ds_read+MFMA of buf[cur]; ONE
// __syncthreads() per step (its compiler-inserted vmcnt(0)+lgkmcnt(0) drain is the
// required wait; t+1 stores target the other buffer -> no intra-step hazard).
// Banded XCD swizzle for A-band L2 reuse (verified r4: FETCH 266->82MB).

template<int KTOT, bool SPLIT_A, bool OUT_F32>
__global__ __launch_bounds__(256) void gemm_kernel(const bh* __restrict__ A0, const bh* __restrict__ A1,
                            const bh* __restrict__ Bw, const float* __restrict__ bias,
                            float* __restrict__ outF, bh* __restrict__ outH) {
    __shared__ alignas(16) bh lds[32768];     // 64KB: buf[2] x { A[128][64] | B[128][64] }
    const int tid = threadIdx.x;
    const int l = tid & 63, w = tid >> 6;
    const int wm = w >> 1, wn = w & 1;
    const int bid = blockIdx.x, nwg = gridDim.x;
    const int swz = (bid & 7) * (nwg >> 3) + (bid >> 3);
    const int rowBase = (swz >> 2) * 128;     // 512 row bands
    const int colBase = (swz & 3) * 128;      // 4 col tiles
    const int lr8 = l >> 3;                   // row within 8-row segment
    const int lc8 = (l & 7) * 8;              // bf16 col within row
    const int rsub = l & 15, g = l >> 4;
    f32x4 acc[4][4] = {};
    const int NT = KTOT / 64;

    auto stage = [&](int t, int bufsel) {
        const int k0 = t * 64;
        const bh* As = A0; int kk = k0;
        if (SPLIT_A && k0 >= 512) { As = A1; kk = k0 - 512; }
        bh* lb = &lds[bufsel * 16384];
#pragma unroll
        for (int i = 0; i < 4; ++i) {
            const int r = w * 32 + i * 8;     // segment base row (wave-uniform)
            const bh* ga = As + (size_t)(rowBase + r + lr8) * 512 + kk + lc8;
            const bh* gb = Bw + (size_t)(colBase + r + lr8) * KTOT + k0 + lc8;
            __builtin_amdgcn_global_load_lds(
                (const __attribute__((address_space(1))) void*)ga,
                (__attribute__((address_space(3))) void*)&lb[r * 64], 16, 0, 0);
            __builtin_amdgcn_global_load_lds(
                (const __attribute__((address_space(1))) void*)gb,
                (__attribute__((address_space(3))) void*)&lb[8192 + r * 64], 16, 0, 0);
        }
    };

    stage(0, 0);
    __syncthreads();                 // vmcnt(0): tile 0 visible
    int cur = 0;
    for (int t = 0; t < NT; ++t) {
        if (t + 1 < NT) stage(t + 1, cur ^ 1);   // issue next tile into other buffer
        const bh* lb = &lds[cur * 16384];
#pragma unroll
        for (int ks = 0; ks < 2; ++ks) {
            bh8 af[4], bfr[4];
#pragma unroll
            for (int m = 0; m < 4; ++m)
                af[m] = *(const bh8*)&lb[(wm * 64 + m * 16 + rsub) * 64 + ks * 32 + g * 8];
#pragma unroll
            for (int n = 0; n < 4; ++n)
                bfr[n] = *(const bh8*)&lb[8192 + (wn * 64 + n * 16 + rsub) * 64 + ks * 32 + g * 8];
#pragma unroll
            for (int m = 0; m < 4; ++m)
#pragma unroll
                for (int n = 0; n < 4; ++n)
                    acc[m][n] = __builtin_amdgcn_mfma_f32_16x16x32_bf16(af[m], bfr[n], acc[m][n], 0, 0, 0);
        }
        __syncthreads();             // drains vmcnt(0) (t+1 landed) + all reads of buf[cur] done
        cur ^= 1;
    }

#pragma unroll
    for (int m = 0; m < 4; ++m)
#pragma unroll
        for (int j = 0; j < 4; ++j) {
            const int row = rowBase + wm * 64 + m * 16 + g * 4 + j;
#pragma unroll
            for (int n = 0; n < 4; ++n) {
                const int col = colBase + wn * 64 + n * 16 + rsub;
                float v = acc[m][n][j] + bias[col];
                if (OUT_F32) outF[(size_t)row * 512 + col] = v;
                else         outH[(size_t)row * 512 + col] = (bh)v;
            }
        }
}

// ---------------- chunked complex scan (3 passes) ----------------
__global__ void scan1_kernel(const bh* __restrict__ Bu, const float* __restrict__ lamRe,
                             const float* __restrict__ lamIm, float* __restrict__ carRe,
                             float* __restrict__ carIm) {
    int b = blockIdx.x >> 7, c = blockIdx.x & (CHUNKS - 1);
    int n = threadIdx.x;
    float lr = lamRe[n], li = lamIm[n];
    float hr = 0.f, hi = 0.f;
    const bh* p = Bu + ((size_t)(b * SEQL + c * CHUNKLN)) * 512;
    for (int i = 0; i < CHUNKLN; ++i) {
        float br = (float)p[n], bi = (float)p[n + 256];
        float nr = lr * hr - li * hi + br;
        float ni = lr * hi + li * hr + bi;
        hr = nr; hi = ni; p += 512;
    }
    carRe[(size_t)blockIdx.x * 256 + n] = hr;
    carIm[(size_t)blockIdx.x * 256 + n] = hi;
}

__global__ void scan2_kernel(const float* __restrict__ carRe, const float* __restrict__ carIm,
                             const float* __restrict__ lamSRe, const float* __restrict__ lamSIm,
                             float* __restrict__ iniRe, float* __restrict__ iniIm) {
    int b = blockIdx.x, n = threadIdx.x;
    float lr = lamSRe[n], li = lamSIm[n];
    float hr = 0.f, hi = 0.f;
    for (int c = 0; c < CHUNKS; ++c) {
        size_t idx = ((size_t)b * CHUNKS + c) * 256 + n;
        iniRe[idx] = hr; iniIm[idx] = hi;
        float cr = carRe[idx], ci = carIm[idx];
        float nr = lr * hr - li * hi + cr;
        float ni = lr * hi + li * hr + ci;
        hr = nr; hi = ni;
    }
}

// pass 3: recompute local scan with carry-in, write h (bf16, in-place over Bu) + tail (planar)
__global__ void scan3_kernel(bh* __restrict__ Bu, const float* __restrict__ lamRe,
                             const float* __restrict__ lamIm, const float* __restrict__ iniRe,
                             const float* __restrict__ iniIm, float* __restrict__ outTail,
                             int tailN) {
    int b = blockIdx.x >> 7, c = blockIdx.x & (CHUNKS - 1);
    int n = threadIdx.x;
    float lr = lamRe[n], li = lamIm[n];
    size_t idx = (size_t)blockIdx.x * 256 + n;
    float hr = iniRe[idx], hi = iniIm[idx];
    bh* p = Bu + ((size_t)(b * SEQL + c * CHUNKLN)) * 512;
    for (int i = 0; i < CHUNKLN; ++i) {
        float br = (float)p[n], bi = (float)p[n + 256];
        float nr = lr * hr - li * hi + br;
        float ni = lr * hi + li * hr + bi;
        hr = nr; hi = ni;
        p[n] = (bh)hr; p[n + 256] = (bh)hi;
        p += 512;
    }
    if (c == CHUNKS - 1) {                 // h[:, L-1]
        if (tailN >= 4096) {               // planar: all re, then all im
            outTail[b * 256 + n]        = hr;
            outTail[2048 + b * 256 + n] = hi;
        } else {
            outTail[b * 256 + n] = hr;
        }
    }
}

// ---------------- launch ----------------
extern "C" void kernel_launch(void* const* d_in, const int* in_sizes, int n_in,
                              void* d_out, int out_size, void* d_ws, size_t ws_size,
                              hipStream_t stream) {
    const float* x        = (const float*)d_in[0];
    const float* W        = (const float*)d_in[1];
    const float* bvec     = (const float*)d_in[2];
    const float* nu_log   = (const float*)d_in[3];
    const float* theta_lg = (const float*)d_in[4];
    const float* gamma_lg = (const float*)d_in[5];
    const float* Bre      = (const float*)d_in[6];
    const float* Bim      = (const float*)d_in[7];
    const float* Cre      = (const float*)d_in[8];
    const float* Cim      = (const float*)d_in[9];
    const float* Dvec     = (const float*)d_in[10];

    char* ws = (char*)d_ws;
    bh* xh   = (bh*)(ws);                                   // 64 MB
    bh* bu   = (bh*)(ws + 67108864);                        // 64 MB (becomes h in-place)
    bh* wbt  = (bh*)(ws + 134217728);                       // 512 KB
    bh* wct  = (bh*)(ws + 134217728 + 524288);              // 1 MB
    float* sm = (float*)(ws + 134217728 + 524288 + 1048576);
    float* bB = sm;               // 512
    float* bD = sm + 512;         // 512
    float* lamRe  = sm + 1024;    // 256
    float* lamIm  = sm + 1280;
    float* lamSRe = sm + 1536;
    float* lamSIm = sm + 1792;
    float* gamma  = sm + 2048;    // 256
    float* carRe  = sm + 2304;                 // 8*128*256 each
    float* carIm  = carRe + (size_t)BATCH * CHUNKS * 256;
    float* iniRe  = carIm + (size_t)BATCH * CHUNKS * 256;
    float* iniIm  = iniRe + (size_t)BATCH * CHUNKS * 256;

    float* outF    = (float*)d_out;
    float* outTail = outF + (size_t)MTOT * DOUTD;
    int tailN = out_size - MTOT * DOUTD;       // 4096 (float view) or 2048

    conv_x_kernel<<<16384, 256, 0, stream>>>((const float4*)x, xh);
    prep0_kernel<<<1, 512, 0, stream>>>(nu_log, theta_lg, gamma_lg, Bre, Bim, bvec, Dvec,
                                        lamRe, lamIm, lamSRe, lamSIm, gamma, bB, bD);
    prepWB_kernel<<<1024, 256, 0, stream>>>(W, Bre, Bim, gamma, wbt);
    prepWC_kernel<<<2048, 256, 0, stream>>>(Cre, Cim, W, Dvec, wct);

    gemm_kernel<512, false, false><<<2048, 256, 0, stream>>>(xh, nullptr, wbt, bB, nullptr, bu);

    scan1_kernel<<<BATCH * CHUNKS, 256, 0, stream>>>(bu, lamRe, lamIm, carRe, carIm);
    scan2_kernel<<<BATCH, 256, 0, stream>>>(carRe, carIm, lamSRe, lamSIm, iniRe, iniIm);
    scan3_kernel<<<BATCH * CHUNKS, 256, 0, stream>>>(bu, lamRe, lamIm, iniRe, iniIm, outTail, tailN);

    gemm_kernel<1024, true, true><<<2048, 256, 0, stream>>>(bu, xh, wct, bD, outF, nullptr);
}